// Round 14
// baseline (193.596 us; speedup 1.0000x reference)
//
#include <hip/hip_runtime.h>

// Problem constants (CompactCrossAttention)
#define Bb   2
#define QL   1024
#define KL   4096
#define Hh   1024
#define NH   16
#define HD   64

#define KSPLIT 4
#define CHUNK  (KL / KSPLIT)   // 1024 keys per block
#define NTT    (CHUNK / 64)    // 16 tiles of 64 keys

typedef unsigned short u16;
typedef __attribute__((ext_vector_type(8))) short bf16x8;     // MFMA A/B frag
typedef __attribute__((ext_vector_type(4))) float f32x4;      // 16x16 C/D frag
typedef __attribute__((ext_vector_type(16))) float f32x16;    // 32x32 C/D frag

#define QSCALE 0.1803368801111204f   // 0.125 * log2(e): scores in log2 domain
#define RTHR   11.0f                 // defer-max threshold (log2 units)

__device__ __forceinline__ u16 f2bf(float f) {
    union { float f; unsigned int u; } v; v.f = f;
    unsigned int r = (v.u + 0x7FFFu + ((v.u >> 16) & 1u)) >> 16;
    return (u16)r;
}

__device__ __forceinline__ unsigned int cvt_pk_bf16(float lo, float hi) {
    unsigned int r;
    asm("v_cvt_pk_bf16_f32 %0, %1, %2" : "=v"(r) : "v"(lo), "v"(hi));
    return r;
}

__device__ __forceinline__ float max3f(float a, float b, float c) {
    float r;
    asm("v_max3_f32 %0, %1, %2, %3" : "=v"(r) : "v"(a), "v"(b), "v"(c));
    return r;
}

// v_permlane32_swap_b32: new_a[l<32]=a[l], new_a[l>=32]=b[l-32];
//                        new_b[l<32]=a[l+32], new_b[l>=32]=b[l]
__device__ __forceinline__ void plane32swap(unsigned int& a, unsigned int& b) {
    asm volatile("v_permlane32_swap_b32 %0, %1" : "+v"(a), "+v"(b));
}

__device__ __forceinline__ void gload16(const void* g, void* l) {
    __builtin_amdgcn_global_load_lds(
        (const __attribute__((address_space(1))) void*)g,
        (__attribute__((address_space(3))) void*)l, 16, 0, 0);
}

// pack 8 fp32 -> 8 bf16 (uint4)
__device__ __forceinline__ uint4 pack8(const float4& f0, const float4& f1) {
    uint4 o;
    o.x = cvt_pk_bf16(f0.x, f0.y);
    o.y = cvt_pk_bf16(f0.z, f0.w);
    o.z = cvt_pk_bf16(f1.x, f1.y);
    o.w = cvt_pk_bf16(f1.z, f1.w);
    return o;
}

// ---------------------------------------------------------------------------
// PREP: weight transposes (swizzled) + activation casts, ONE launch.
// ---------------------------------------------------------------------------
__global__ __launch_bounds__(256) void prep_all(const float* __restrict__ wq,
                                                const float* __restrict__ wkv,
                                                const float* __restrict__ wout,
                                                const float* __restrict__ qact,
                                                const float* __restrict__ kvact,
                                                u16* __restrict__ wqT,
                                                u16* __restrict__ wkvT,
                                                u16* __restrict__ woutT,
                                                u16* __restrict__ qb,
                                                u16* __restrict__ kvb) {
    __shared__ float T[64][65];
    int bid = blockIdx.x;
    if (bid >= 1024) {
        bid -= 1024;
        const float* in; u16* out;
        if (bid < 1024) { in = qact;  out = qb;  }
        else            { in = kvact; out = kvb; bid -= 1024; }
        const size_t i = ((size_t)bid * 256 + threadIdx.x) * 8;
        float4 f0 = *reinterpret_cast<const float4*>(in + i);
        float4 f1 = *reinterpret_cast<const float4*>(in + i + 4);
        *reinterpret_cast<uint4*>(out + i) = pack8(f0, f1);
        return;
    }
    const float* in; u16* out; int C;
    if (bid < 256)      { in = wq;   out = wqT;   C = 1024; }
    else if (bid < 768) { in = wkv;  out = wkvT;  C = 2048; bid -= 256; }
    else                { in = wout; out = woutT; C = 1024; bid -= 768; }
    const int nc = C >> 6;
    const int c0 = (bid % nc) * 64;
    const int r0 = (bid / nc) * 64;
    const int t  = threadIdx.x;
    const int tx = t & 15, ty = t >> 4;
#pragma unroll
    for (int p = 0; p < 4; ++p) {
        const int r = ty + p * 16;
        float4 v = *reinterpret_cast<const float4*>(in + (size_t)(r0 + r) * C + c0 + tx * 4);
        T[r][tx * 4 + 0] = v.x; T[r][tx * 4 + 1] = v.y;
        T[r][tx * 4 + 2] = v.z; T[r][tx * 4 + 3] = v.w;
    }
    __syncthreads();
#pragma unroll
    for (int p = 0; p < 4; ++p) {
        const int c = ty + p * 16;
        const int n = c0 + c;
        ushort4 o;
        o.x = f2bf(T[tx * 4 + 0][c]); o.y = f2bf(T[tx * 4 + 1][c]);
        o.z = f2bf(T[tx * 4 + 2][c]); o.w = f2bf(T[tx * 4 + 3][c]);
        const int kb   = r0 + tx * 4;
        const int kout = (kb & ~63) | ((((kb >> 3) & 7) ^ (n & 7)) << 3) | (kb & 7);
        *reinterpret_cast<ushort4*>(out + (size_t)n * 1024 + kout) = o;
    }
}

// ---------------------------------------------------------------------------
// FUSED Q + KV projection GEMM — m97 structure (unchanged from round 12).
// ---------------------------------------------------------------------------
__global__ __launch_bounds__(256) void qkvgemm(const u16* __restrict__ Aq,
                                               const u16* __restrict__ Akv,
                                               const u16* __restrict__ wqT,
                                               const u16* __restrict__ wkvT,
                                               u16* __restrict__ Qb,
                                               u16* __restrict__ KT,
                                               u16* __restrict__ VT) {
    __shared__ u16 As[128 * 64];
    __shared__ u16 Bs[128 * 64];
    const int tid = threadIdx.x, lane = tid & 63, w = tid >> 6;
    const int wr = w >> 1, wc = w & 1;
    const int x7 = lane & 7;
    const int lrow = lane >> 3, lcol = (lane & 7) * 8;
    const int swcol = lcol ^ ((lrow & 7) << 3);   // A source granule XOR

    if (blockIdx.x < 1024) {
        const int id = blockIdx.x;
        const int sw = (id & 7) * 128 + (id >> 3);
        const int bx = sw % 16, by = sw / 16;
        const int row0 = by * 128, col0 = bx * 128;
        const int MROW = wr * 64;

        f32x4 acc[4][4];
#pragma unroll
        for (int m = 0; m < 4; ++m)
#pragma unroll
            for (int n = 0; n < 4; ++n) acc[m][n] = (f32x4){0.f, 0.f, 0.f, 0.f};

        auto stage = [&](int k0) {
            __syncthreads();
#pragma unroll
            for (int p = 0; p < 4; ++p) {
                const int base = w * 512 + p * 2048;
                const int row  = (base >> 6) + lrow;
                gload16(Akv + (size_t)(row0 + row) * 1024 + k0 + swcol, &As[base]);
                gload16(wkvT + (size_t)(col0 + row) * 1024 + k0 + lcol, &Bs[base]);
            }
            __syncthreads();
        };

        if (col0 < 1024) {
            for (int k0 = 0; k0 < 1024; k0 += 64) {
                stage(k0);
#pragma unroll
                for (int kk = 0; kk < 2; ++kk) {
                    bf16x8 af[4], bfr[4];
                    const int G = ((kk * 4 + (lane >> 4)) ^ x7) * 8;
#pragma unroll
                    for (int m = 0; m < 4; ++m)
                        af[m] = *reinterpret_cast<const bf16x8*>(
                            &As[(MROW + m * 16 + (lane & 15)) * 64 + G]);
#pragma unroll
                    for (int n = 0; n < 4; ++n)
                        bfr[n] = *reinterpret_cast<const bf16x8*>(
                            &Bs[(wc * 64 + n * 16 + (lane & 15)) * 64 + G]);
#pragma unroll
                    for (int m = 0; m < 4; ++m)
#pragma unroll
                        for (int n = 0; n < 4; ++n)
                            acc[m][n] = __builtin_amdgcn_mfma_f32_16x16x32_bf16(
                                bfr[n], af[m], acc[m][n], 0, 0, 0);
                }
            }
#pragma unroll
            for (int m = 0; m < 4; ++m) {
                const int gr  = row0 + MROW + m * 16 + (lane & 15);
                const int b   = gr >> 12;
                const int k   = gr & 4095;
                const int kt_i = k >> 6, k_in = k & 63;
#pragma unroll
                for (int n = 0; n < 4; ++n) {
                    const int gc0 = col0 + wc * 64 + n * 16 + (lane >> 4) * 4;
                    const int h   = gc0 >> 6, d0 = gc0 & 63;
                    u16* blob = KT + (((size_t)((b << 4) + h) * 64 + kt_i) << 9) * 8;
                    const int og = k_in * 8 + ((d0 >> 3) ^ (k_in & 7));
                    ushort4 pk;
                    pk.x = f2bf(acc[m][n][0]); pk.y = f2bf(acc[m][n][1]);
                    pk.z = f2bf(acc[m][n][2]); pk.w = f2bf(acc[m][n][3]);
                    *reinterpret_cast<ushort4*>(&blob[og * 8 + (d0 & 7)]) = pk;
                }
            }
        } else {
            for (int k0 = 0; k0 < 1024; k0 += 64) {
                stage(k0);
#pragma unroll
                for (int kk = 0; kk < 2; ++kk) {
                    bf16x8 af[4], bfr[4];
                    const int G = ((kk * 4 + (lane >> 4)) ^ x7) * 8;
#pragma unroll
                    for (int m = 0; m < 4; ++m)
                        af[m] = *reinterpret_cast<const bf16x8*>(
                            &As[(MROW + m * 16 + (lane & 15)) * 64 + G]);
#pragma unroll
                    for (int n = 0; n < 4; ++n)
                        bfr[n] = *reinterpret_cast<const bf16x8*>(
                            &Bs[(wc * 64 + n * 16 + (lane & 15)) * 64 + G]);
#pragma unroll
                    for (int m = 0; m < 4; ++m)
#pragma unroll
                        for (int n = 0; n < 4; ++n)
                            acc[m][n] = __builtin_amdgcn_mfma_f32_16x16x32_bf16(
                                af[m], bfr[n], acc[m][n], 0, 0, 0);
                }
            }
#pragma unroll
            for (int m = 0; m < 4; ++m) {
                const int gr0 = row0 + MROW + m * 16 + (lane >> 4) * 4;
                const int b   = gr0 >> 12;
                const int k   = gr0 & 4095;
                const int kt_i = k >> 6, k_in = k & 63;
#pragma unroll
                for (int n = 0; n < 4; ++n) {
                    const int gc = col0 + wc * 64 + n * 16 + (lane & 15);
                    const int h  = (gc & 1023) >> 6, d = gc & 63;
                    u16* blob = VT + (((size_t)((b << 4) + h) * 64 + kt_i) << 9) * 8;
                    const int og = d * 8 + ((k_in >> 3) ^ (d & 7));
                    ushort4 pk;
                    pk.x = f2bf(acc[m][n][0]); pk.y = f2bf(acc[m][n][1]);
                    pk.z = f2bf(acc[m][n][2]); pk.w = f2bf(acc[m][n][3]);
                    *reinterpret_cast<ushort4*>(&blob[og * 8 + (k_in & 7)]) = pk;
                }
            }
        }
    } else {
        const int id = blockIdx.x - 1024;
        const int sw = (id & 7) * 32 + (id >> 3);
        const int bx = sw % 8, by = sw / 8;
        const int row0 = by * 64, col0 = bx * 128;
        const int MROW = wr * 32;

        f32x4 acc[2][4];
#pragma unroll
        for (int m = 0; m < 2; ++m)
#pragma unroll
            for (int n = 0; n < 4; ++n) acc[m][n] = (f32x4){0.f, 0.f, 0.f, 0.f};

        for (int k0 = 0; k0 < 1024; k0 += 64) {
            __syncthreads();
#pragma unroll
            for (int p = 0; p < 2; ++p) {
                const int base = w * 512 + p * 2048;
                const int row  = (base >> 6) + lrow;
                gload16(Aq + (size_t)(row0 + row) * 1024 + k0 + swcol, &As[base]);
            }
#pragma unroll
            for (int p = 0; p < 4; ++p) {
                const int base = w * 512 + p * 2048;
                const int row  = (base >> 6) + lrow;
                gload16(wqT + (size_t)(col0 + row) * 1024 + k0 + lcol, &Bs[base]);
            }
            __syncthreads();
#pragma unroll
            for (int kk = 0; kk < 2; ++kk) {
                bf16x8 af[2], bfr[4];
                const int G = ((kk * 4 + (lane >> 4)) ^ x7) * 8;
#pragma unroll
                for (int m = 0; m < 2; ++m)
                    af[m] = *reinterpret_cast<const bf16x8*>(
                        &As[(MROW + m * 16 + (lane & 15)) * 64 + G]);
#pragma unroll
                for (int n = 0; n < 4; ++n)
                    bfr[n] = *reinterpret_cast<const bf16x8*>(
                        &Bs[(wc * 64 + n * 16 + (lane & 15)) * 64 + G]);
#pragma unroll
                for (int m = 0; m < 2; ++m)
#pragma unroll
                    for (int n = 0; n < 4; ++n)
                        acc[m][n] = __builtin_amdgcn_mfma_f32_16x16x32_bf16(
                            af[m], bfr[n], acc[m][n], 0, 0, 0);
            }
        }
#pragma unroll
        for (int m = 0; m < 2; ++m)
#pragma unroll
            for (int n = 0; n < 4; ++n) {
                const int gc = col0 + wc * 64 + n * 16 + (lane & 15);
#pragma unroll
                for (int r = 0; r < 4; ++r) {
                    const int gr = row0 + MROW + m * 16 + (lane >> 4) * 4 + r;
                    Qb[(size_t)gr * 1024 + gc] = f2bf(acc[m][n][r] * QSCALE);
                }
            }
    }
}

// ---------------------------------------------------------------------------
// Split-K bf16 flash attention (v13 body, KSPLIT=4): 32x32x16 MFMA +
// in-register P via cvt_pk + permlane32_swap.  4 blocks/CU for cross-block
// pipe overlap.  Grid: KSPLIT * B * NH * (QL/128) = 1024 blocks.
// ---------------------------------------------------------------------------
__global__ __launch_bounds__(256, 2) void attn_mfma(const u16* __restrict__ Qb,
                                                    const u16* __restrict__ KT,
                                                    const u16* __restrict__ VT2,
                                                    float* __restrict__ Op,
                                                    float* __restrict__ m_ws,
                                                    float* __restrict__ l_ws) {
    __shared__ u16 Ks[2][4096];   // [key][slot*8], slot = gl ^ (key&7)
    __shared__ u16 Vs[2][4096];   // [d][slot*8],   slot = gl ^ (d&7)

    const int bid0 = blockIdx.x;
    const int bid  = (bid0 & 7) * 128 + (bid0 >> 3);   // XCD swizzle (1024 blocks)
    const int qb   = bid & 7;
    const int h    = (bid >> 3) & 15;
    const int b    = (bid >> 7) & 1;
    const int c    = bid >> 8;        // 0..3
    const int tid  = threadIdx.x;
    const int lane = tid & 63;
    const int w    = tid >> 6;
    const int q    = lane & 31;       // this lane's q column
    const int hl   = lane >> 5;       // half (k-element group)
    const int l7   = lane & 7;
    const int q0   = qb * 128;
    const int bh   = b * NH + h;

    // Q B-frags: qa[dc](lane,e) = Q[q][d = dc*16 + hl*8 + e]
    bf16x8 qa[4];
    {
        const u16* qsrc = Qb + (size_t)(b * QL + q0 + w * 32 + q) * Hh
                          + h * HD + hl * 8;
#pragma unroll
        for (int dc = 0; dc < 4; ++dc)
            qa[dc] = *reinterpret_cast<const bf16x8*>(qsrc + dc * 16);
    }
    asm volatile("s_waitcnt vmcnt(0)" ::: "memory");

    float m_i = -1e30f, l_i = 0.f;
    f32x16 accO[2];
#pragma unroll
    for (int d2 = 0; d2 < 2; ++d2)
#pragma unroll
        for (int r = 0; r < 16; ++r) accO[d2][r] = 0.f;

    // hoisted LDS addressing
    const u16* Kb0 = &Ks[0][q * 64];
    const u16* Vb0 = &Vs[0][q * 64];
    int off[4];
#pragma unroll
    for (int j = 0; j < 4; ++j) off[j] = (((j * 2 + hl) ^ l7) << 3);

    // staging pointers
    const size_t tb0 = ((size_t)bh * 64 + c * NTT) * 4096;
    const u16* kpt = KT  + tb0 + (size_t)(w * 64 + lane) * 8 + 1024;
    const u16* vpt = VT2 + tb0 + (size_t)(w * 64 + lane) * 8 + 1024;
    u16* kdst[2] = { &Ks[0][w * 512], &Ks[1][w * 512] };
    u16* vdst[2] = { &Vs[0][w * 512], &Vs[1][w * 512] };

    gload16(kpt - 1024, kdst[0]);
    gload16(kpt + 1024, kdst[0] + 2048);
    gload16(vpt - 1024, vdst[0]);
    gload16(vpt + 1024, vdst[0] + 2048);

    auto tile = [&](int CUR, int t) {
        __builtin_amdgcn_s_barrier();
        if (t + 1 < NTT) {
            kpt += 4096; vpt += 4096;
            gload16(kpt - 1024, kdst[CUR ^ 1]);
            gload16(kpt + 1024, kdst[CUR ^ 1] + 2048);
            gload16(vpt - 1024, vdst[CUR ^ 1]);
            gload16(vpt + 1024, vdst[CUR ^ 1] + 2048);
            asm volatile("s_waitcnt vmcnt(4)" ::: "memory");
        } else {
            asm volatile("s_waitcnt vmcnt(0)" ::: "memory");
        }
        __builtin_amdgcn_sched_barrier(0);
        __builtin_amdgcn_s_barrier();

        // QK^T: sc[kc][reg] = S[key = kc*32 + (reg&3)+8*(reg>>2)+4*hl][q]
        f32x16 sc[2];
        __builtin_amdgcn_s_setprio(1);
#pragma unroll
        for (int kc = 0; kc < 2; ++kc) {
            f32x16 z;
#pragma unroll
            for (int r = 0; r < 16; ++r) z[r] = 0.f;
#pragma unroll
            for (int dc = 0; dc < 4; ++dc) {
                bf16x8 kf = *reinterpret_cast<const bf16x8*>(
                    Kb0 + CUR * 4096 + kc * 2048 + off[dc]);
                z = __builtin_amdgcn_mfma_f32_32x32x16_bf16(kf, qa[dc], z, 0, 0, 0);
            }
            sc[kc] = z;
        }
        __builtin_amdgcn_s_setprio(0);

        // max over this lane's 32 scores, then combine lane pair (xor 32)
        float mx = max3f(sc[0][0], sc[0][1], sc[0][2]);
#pragma unroll
        for (int i = 3; i + 1 < 32; i += 2)
            mx = max3f(mx, sc[i >> 4][i & 15], sc[(i + 1) >> 4][(i + 1) & 15]);
        mx = fmaxf(mx, sc[1][15]);
        mx = fmaxf(mx, __shfl_xor(mx, 32));

        if (__any(mx > m_i + RTHR)) {          // defer-max
            const float mnew = fmaxf(m_i, mx);
            const float al   = exp2f(m_i - mnew);
            m_i = mnew;
            l_i *= al;
#pragma unroll
            for (int d2 = 0; d2 < 2; ++d2)
#pragma unroll
                for (int r = 0; r < 16; ++r) accO[d2][r] *= al;
        }
#pragma unroll
        for (int kc = 0; kc < 2; ++kc)
#pragma unroll
            for (int r = 0; r < 16; ++r) sc[kc][r] = exp2f(sc[kc][r] - m_i);

        // l: in-lane pairwise sum + cross-half shfl
        {
            float p0 = sc[0][0], p1 = sc[0][1], p2 = sc[0][2], p3 = sc[0][3];
#pragma unroll
            for (int i = 4; i < 16; i += 4) {
                p0 += sc[0][i];     p1 += sc[0][i + 1];
                p2 += sc[0][i + 2]; p3 += sc[0][i + 3];
            }
#pragma unroll
            for (int i = 0; i < 16; i += 4) {
                p0 += sc[1][i];     p1 += sc[1][i + 1];
                p2 += sc[1][i + 2]; p3 += sc[1][i + 3];
            }
            float sum = (p0 + p1) + (p2 + p3);
            sum += __shfl_xor(sum, 32);
            l_i += sum;
        }

        // PV: per k-chunk kk, build P B-frag in registers via permlane32_swap
        __builtin_amdgcn_s_setprio(1);
#pragma unroll
        for (int kk = 0; kk < 4; ++kk) {
            const int kc  = kk >> 1;
            const int rb  = (kk & 1) * 8;
            unsigned int X0 = cvt_pk_bf16(sc[kc][rb + 0], sc[kc][rb + 1]);
            unsigned int X1 = cvt_pk_bf16(sc[kc][rb + 2], sc[kc][rb + 3]);
            unsigned int Y0 = cvt_pk_bf16(sc[kc][rb + 4], sc[kc][rb + 5]);
            unsigned int Y1 = cvt_pk_bf16(sc[kc][rb + 6], sc[kc][rb + 7]);
            plane32swap(X0, Y0);
            plane32swap(X1, Y1);
            uint4 wv = make_uint4(X0, X1, Y0, Y1);
            bf16x8 pf;
            __builtin_memcpy(&pf, &wv, 16);
            bf16x8 vf0 = *reinterpret_cast<const bf16x8*>(
                Vb0 + CUR * 4096 + off[kk]);
            bf16x8 vf1 = *reinterpret_cast<const bf16x8*>(
                Vb0 + CUR * 4096 + 2048 + off[kk]);
            accO[0] = __builtin_amdgcn_mfma_f32_32x32x16_bf16(vf0, pf, accO[0], 0, 0, 0);
            accO[1] = __builtin_amdgcn_mfma_f32_32x32x16_bf16(vf1, pf, accO[1], 0, 0, 0);
        }
        __builtin_amdgcn_s_setprio(0);
    };

    for (int t = 0; t < NTT; t += 2) {
        tile(0, t);
        tile(1, t + 1);
    }

    // epilogue: unnormalized O (float4 stores) + per-row m,l
    float* opc = Op + (size_t)c * ((size_t)Bb * QL * Hh)
                 + (size_t)(b * QL + q0 + w * 32 + q) * Hh + h * HD;
#pragma unroll
    for (int d2 = 0; d2 < 2; ++d2) {
#pragma unroll
        for (int b2 = 0; b2 < 4; ++b2) {
            float4 v = make_float4(accO[d2][4 * b2 + 0], accO[d2][4 * b2 + 1],
                                   accO[d2][4 * b2 + 2], accO[d2][4 * b2 + 3]);
            *reinterpret_cast<float4*>(opc + d2 * 32 + b2 * 8 + hl * 4) = v;
        }
    }
    if (hl == 0) {
        const int idx = ((c * Bb + b) * NH + h) * QL + q0 + w * 32 + q;
        m_ws[idx] = m_i;
        l_ws[idx] = l_i;
    }
}

// ---------------------------------------------------------------------------
// Output GEMM with FUSED 4-way split-K combine in A-staging.  BMT=64.
// ---------------------------------------------------------------------------
__global__ __launch_bounds__(256) void ogemm(const float* __restrict__ Op,
                                             const float* __restrict__ m_ws,
                                             const float* __restrict__ l_ws,
                                             const u16* __restrict__ Bt,
                                             float* __restrict__ C) {
    __shared__ u16 As[64 * 64];
    __shared__ u16 Bs[128 * 64];
    const int nwg = gridDim.x * gridDim.y;
    const int id  = blockIdx.y * gridDim.x + blockIdx.x;
    const int sw  = (id & 7) * (nwg >> 3) + (id >> 3);
    const int bx  = sw % gridDim.x, by = sw / gridDim.x;
    const int tid = threadIdx.x, lane = tid & 63, w = tid >> 6;
    const int wr = w >> 1, wc = w & 1;
    const int row0 = by * 64, col0 = bx * 128;
    const int MROW = wr * 32;
    const int x7   = lane & 7;

    f32x4 acc[2][4];
#pragma unroll
    for (int m = 0; m < 2; ++m)
#pragma unroll
        for (int n = 0; n < 4; ++n) acc[m][n] = (f32x4){0.f, 0.f, 0.f, 0.f};

    const int lrow = lane >> 3, lcol = (lane & 7) * 8;
    const int arow = tid >> 3, acol8 = (tid & 7) * 8;
    const int aphys = acol8 ^ ((arow & 7) << 3);

    for (int k0 = 0; k0 < 1024; k0 += 64) {
        __syncthreads();
        const int h_ = k0 >> 6;   // uniform per step
#pragma unroll
        for (int p = 0; p < 2; ++p) {
            const int r    = p * 32 + arow;
            const int grow = row0 + r;
            const int b_   = grow >> 10, q_ = grow & 1023;
            const int idx  = (((b_ << 4) + h_) << 10) + q_;
            float mm[4], ll[4];
#pragma unroll
            for (int s2 = 0; s2 < 4; ++s2) {
                mm[s2] = m_ws[idx + s2 * 32768];
                ll[s2] = l_ws[idx + s2 * 32768];
            }
            const float ms = fmaxf(fmaxf(mm[0], mm[1]), fmaxf(mm[2], mm[3]));
            float aw[4]; float den = 0.f;
#pragma unroll
            for (int s2 = 0; s2 < 4; ++s2) {
                aw[s2] = exp2f(mm[s2] - ms);
                den += ll[s2] * aw[s2];
            }
            const float inv = 1.f / den;
#pragma unroll
            for (int s2 = 0; s2 < 4; ++s2) aw[s2] *= inv;

            float4 f0 = make_float4(0.f, 0.f, 0.f, 0.f);
            float4 f1 = make_float4(0.f, 0.f, 0.f, 0.f);
#pragma unroll
            for (int s2 = 0; s2 < 4; ++s2) {
                const float* o0 = Op + (size_t)s2 * ((size_t)Bb * QL * Hh)
                                  + (size_t)grow * 1024 + k0 + acol8;
                float4 x0 = *reinterpret_cast<const float4*>(o0);
                float4 x1 = *reinterpret_cast<const float4*>(o0 + 4);
                f0.x += x0.x * aw[s2]; f0.y += x0.y * aw[s2];
                f0.z += x0.z * aw[s2]; f0.w += x0.w * aw[s2];
                f1.x += x1.x * aw[s2]; f1.y += x1.y * aw[s2];
                f1.z += x1.z * aw[s2]; f1.w += x1.w * aw[s2];
            }
            *reinterpret_cast<uint4*>(&As[r * 64 + aphys]) = pack8(f0, f1);
        }
#pragma unroll
        for (int p = 0; p < 4; ++p) {
            const int base = w * 512 + p * 2048;
            const int row  = (base >> 6) + lrow;
            gload16(Bt + (size_t)(col0 + row) * 1024 + k0 + lcol, &Bs[base]);
        }
        __syncthreads();
#pragma unroll
        for (int kk = 0; kk < 2; ++kk) {
            bf16x8 af[2], bfr[4];
            const int G = ((kk * 4 + (lane >> 4)) ^ x7) * 8;
#pragma unroll
            for (int m = 0; m < 2; ++m)
                af[m] = *reinterpret_cast<const bf16x8*>(
                    &As[(MROW + m * 16 + (lane & 15)) * 64 + G]);
#pragma unroll
            for (int n = 0; n < 4; ++n)
                bfr[n] = *reinterpret_cast<const bf16x8*>(
                    &Bs[(wc * 64 + n * 16 + (lane & 15)) * 64 + G]);
#pragma unroll
            for (int m = 0; m < 2; ++m)
#pragma unroll
                for (int n = 0; n < 4; ++n)
                    acc[m][n] = __builtin_amdgcn_mfma_f32_16x16x32_bf16(
                        af[m], bfr[n], acc[m][n], 0, 0, 0);
        }
    }
#pragma unroll
    for (int m = 0; m < 2; ++m)
#pragma unroll
        for (int n = 0; n < 4; ++n) {
            const int gc = col0 + wc * 64 + n * 16 + (lane & 15);
#pragma unroll
            for (int r = 0; r < 4; ++r) {
                const int gr = row0 + MROW + m * 16 + (lane >> 4) * 4 + r;
                C[(size_t)gr * 1024 + gc] = acc[m][n][r];
            }
        }
}

// ---------------------------------------------------------------------------
// Launch.  Workspace (ws >= 80 MB):
//   0-16 KT | 16-32 VT | 32-64 Opart[4] (kvbf overlays 32-48, qbf 48-52)
//  64-68 Qb | 68-72 wkvT | 72-74 wqT | 74-76 woutT | 76-77 m_ws,l_ws
// ---------------------------------------------------------------------------
extern "C" void kernel_launch(void* const* d_in, const int* in_sizes, int n_in,
                              void* d_out, int out_size, void* d_ws, size_t ws_size,
                              hipStream_t stream) {
    const float* query     = (const float*)d_in[0];
    const float* key_value = (const float*)d_in[1];
    const float* w_q       = (const float*)d_in[2];
    const float* w_kv      = (const float*)d_in[3];
    const float* w_out     = (const float*)d_in[4];
    float* out = (float*)d_out;

    char* ws = (char*)d_ws;
    const size_t MB = 1024 * 1024;
    u16*   KT    = (u16*)(ws);
    u16*   VT    = (u16*)(ws + 16 * MB);
    float* Opart = (float*)(ws + 32 * MB);   // 32 MB, written by attn
    u16*   kvbf  = (u16*)(ws + 32 * MB);     // overlay, dead after qkvgemm
    u16*   qbf   = (u16*)(ws + 48 * MB);     // overlay, dead after qkvgemm
    u16*   Qb    = (u16*)(ws + 64 * MB);
    u16*   wkvT  = (u16*)(ws + 68 * MB);
    u16*   wqT   = (u16*)(ws + 72 * MB);
    u16*   woutT = (u16*)(ws + 74 * MB);
    float* m_wsp = (float*)(ws + 76 * MB);
    float* l_wsp = (float*)(ws + 76 * MB + 512 * 1024);

    dim3 blk(256);

    // 1) weight transposes (swizzled) + activation casts, one launch
    prep_all<<<6144, blk, 0, stream>>>(w_q, w_kv, w_out, query, key_value,
                                       wqT, wkvT, woutT, qbf, kvbf);

    // 2) FUSED Q + KV projections (m97 structure)
    qkvgemm<<<1280, blk, 0, stream>>>(qbf, kvbf, wqT, wkvT, Qb, KT, VT);

    // 3) split-K flash attention (KSPLIT=4, 1024 blocks = 4/CU)
    attn_mfma<<<dim3(KSPLIT * 256), blk, 0, stream>>>(
        Qb, KT, VT, Opart, m_wsp, l_wsp);

    // 4) output GEMM (fused 4-way split-K combine)
    ogemm<<<dim3(8, 32), blk, 0, stream>>>(Opart, m_wsp, l_wsp, woutT, out);
}

// Round 15
// 150.578 us; speedup vs baseline: 1.2857x; 1.2857x over previous
//
#include <hip/hip_runtime.h>

// Problem constants (CompactCrossAttention)
#define Bb   2
#define QL   1024
#define KL   4096
#define Hh   1024
#define NH   16
#define HD   64

#define KSPLIT 2
#define CHUNK  (KL / KSPLIT)   // 2048 keys per block
#define NTT    (CHUNK / 64)    // 32 tiles of 64 keys

typedef unsigned short u16;
typedef __attribute__((ext_vector_type(8))) short bf16x8;     // MFMA A/B frag
typedef __attribute__((ext_vector_type(4))) float f32x4;      // 16x16 C/D frag
typedef __attribute__((ext_vector_type(16))) float f32x16;    // 32x32 C/D frag

#define QSCALE 0.1803368801111204f   // 0.125 * log2(e): scores in log2 domain
#define RTHR   11.0f                 // defer-max threshold (log2 units)

__device__ __forceinline__ u16 f2bf(float f) {
    union { float f; unsigned int u; } v; v.f = f;
    unsigned int r = (v.u + 0x7FFFu + ((v.u >> 16) & 1u)) >> 16;
    return (u16)r;
}

__device__ __forceinline__ unsigned int cvt_pk_bf16(float lo, float hi) {
    unsigned int r;
    asm("v_cvt_pk_bf16_f32 %0, %1, %2" : "=v"(r) : "v"(lo), "v"(hi));
    return r;
}

__device__ __forceinline__ float max3f(float a, float b, float c) {
    float r;
    asm("v_max3_f32 %0, %1, %2, %3" : "=v"(r) : "v"(a), "v"(b), "v"(c));
    return r;
}

// v_permlane32_swap_b32: new_a[l<32]=a[l], new_a[l>=32]=b[l-32];
//                        new_b[l<32]=a[l+32], new_b[l>=32]=b[l]
__device__ __forceinline__ void plane32swap(unsigned int& a, unsigned int& b) {
    asm volatile("v_permlane32_swap_b32 %0, %1" : "+v"(a), "+v"(b));
}

__device__ __forceinline__ void gload16(const void* g, void* l) {
    __builtin_amdgcn_global_load_lds(
        (const __attribute__((address_space(1))) void*)g,
        (__attribute__((address_space(3))) void*)l, 16, 0, 0);
}

// pack 8 fp32 -> 8 bf16 (uint4)
__device__ __forceinline__ uint4 pack8(const float4& f0, const float4& f1) {
    uint4 o;
    o.x = cvt_pk_bf16(f0.x, f0.y);
    o.y = cvt_pk_bf16(f0.z, f0.w);
    o.z = cvt_pk_bf16(f1.x, f1.y);
    o.w = cvt_pk_bf16(f1.z, f1.w);
    return o;
}

// ---------------------------------------------------------------------------
// PREP: weight transposes (swizzled) + activation casts, ONE launch.
// ---------------------------------------------------------------------------
__global__ __launch_bounds__(256) void prep_all(const float* __restrict__ wq,
                                                const float* __restrict__ wkv,
                                                const float* __restrict__ wout,
                                                const float* __restrict__ qact,
                                                const float* __restrict__ kvact,
                                                u16* __restrict__ wqT,
                                                u16* __restrict__ wkvT,
                                                u16* __restrict__ woutT,
                                                u16* __restrict__ qb,
                                                u16* __restrict__ kvb) {
    __shared__ float T[64][65];
    int bid = blockIdx.x;
    if (bid >= 1024) {
        bid -= 1024;
        const float* in; u16* out;
        if (bid < 1024) { in = qact;  out = qb;  }
        else            { in = kvact; out = kvb; bid -= 1024; }
        const size_t i = ((size_t)bid * 256 + threadIdx.x) * 8;
        float4 f0 = *reinterpret_cast<const float4*>(in + i);
        float4 f1 = *reinterpret_cast<const float4*>(in + i + 4);
        *reinterpret_cast<uint4*>(out + i) = pack8(f0, f1);
        return;
    }
    const float* in; u16* out; int C;
    if (bid < 256)      { in = wq;   out = wqT;   C = 1024; }
    else if (bid < 768) { in = wkv;  out = wkvT;  C = 2048; bid -= 256; }
    else                { in = wout; out = woutT; C = 1024; bid -= 768; }
    const int nc = C >> 6;
    const int c0 = (bid % nc) * 64;
    const int r0 = (bid / nc) * 64;
    const int t  = threadIdx.x;
    const int tx = t & 15, ty = t >> 4;
#pragma unroll
    for (int p = 0; p < 4; ++p) {
        const int r = ty + p * 16;
        float4 v = *reinterpret_cast<const float4*>(in + (size_t)(r0 + r) * C + c0 + tx * 4);
        T[r][tx * 4 + 0] = v.x; T[r][tx * 4 + 1] = v.y;
        T[r][tx * 4 + 2] = v.z; T[r][tx * 4 + 3] = v.w;
    }
    __syncthreads();
#pragma unroll
    for (int p = 0; p < 4; ++p) {
        const int c = ty + p * 16;
        const int n = c0 + c;
        ushort4 o;
        o.x = f2bf(T[tx * 4 + 0][c]); o.y = f2bf(T[tx * 4 + 1][c]);
        o.z = f2bf(T[tx * 4 + 2][c]); o.w = f2bf(T[tx * 4 + 3][c]);
        const int kb   = r0 + tx * 4;
        const int kout = (kb & ~63) | ((((kb >> 3) & 7) ^ (n & 7)) << 3) | (kb & 7);
        *reinterpret_cast<ushort4*>(out + (size_t)n * 1024 + kout) = o;
    }
}

// ---------------------------------------------------------------------------
// FUSED Q + KV projection GEMM — m97 structure (unchanged from round 12).
// ---------------------------------------------------------------------------
__global__ __launch_bounds__(256) void qkvgemm(const u16* __restrict__ Aq,
                                               const u16* __restrict__ Akv,
                                               const u16* __restrict__ wqT,
                                               const u16* __restrict__ wkvT,
                                               u16* __restrict__ Qb,
                                               u16* __restrict__ KT,
                                               u16* __restrict__ VT) {
    __shared__ u16 As[128 * 64];
    __shared__ u16 Bs[128 * 64];
    const int tid = threadIdx.x, lane = tid & 63, w = tid >> 6;
    const int wr = w >> 1, wc = w & 1;
    const int x7 = lane & 7;
    const int lrow = lane >> 3, lcol = (lane & 7) * 8;
    const int swcol = lcol ^ ((lrow & 7) << 3);   // A source granule XOR

    if (blockIdx.x < 1024) {
        const int id = blockIdx.x;
        const int sw = (id & 7) * 128 + (id >> 3);
        const int bx = sw % 16, by = sw / 16;
        const int row0 = by * 128, col0 = bx * 128;
        const int MROW = wr * 64;

        f32x4 acc[4][4];
#pragma unroll
        for (int m = 0; m < 4; ++m)
#pragma unroll
            for (int n = 0; n < 4; ++n) acc[m][n] = (f32x4){0.f, 0.f, 0.f, 0.f};

        auto stage = [&](int k0) {
            __syncthreads();
#pragma unroll
            for (int p = 0; p < 4; ++p) {
                const int base = w * 512 + p * 2048;
                const int row  = (base >> 6) + lrow;
                gload16(Akv + (size_t)(row0 + row) * 1024 + k0 + swcol, &As[base]);
                gload16(wkvT + (size_t)(col0 + row) * 1024 + k0 + lcol, &Bs[base]);
            }
            __syncthreads();
        };

        if (col0 < 1024) {
            for (int k0 = 0; k0 < 1024; k0 += 64) {
                stage(k0);
#pragma unroll
                for (int kk = 0; kk < 2; ++kk) {
                    bf16x8 af[4], bfr[4];
                    const int G = ((kk * 4 + (lane >> 4)) ^ x7) * 8;
#pragma unroll
                    for (int m = 0; m < 4; ++m)
                        af[m] = *reinterpret_cast<const bf16x8*>(
                            &As[(MROW + m * 16 + (lane & 15)) * 64 + G]);
#pragma unroll
                    for (int n = 0; n < 4; ++n)
                        bfr[n] = *reinterpret_cast<const bf16x8*>(
                            &Bs[(wc * 64 + n * 16 + (lane & 15)) * 64 + G]);
#pragma unroll
                    for (int m = 0; m < 4; ++m)
#pragma unroll
                        for (int n = 0; n < 4; ++n)
                            acc[m][n] = __builtin_amdgcn_mfma_f32_16x16x32_bf16(
                                bfr[n], af[m], acc[m][n], 0, 0, 0);
                }
            }
#pragma unroll
            for (int m = 0; m < 4; ++m) {
                const int gr  = row0 + MROW + m * 16 + (lane & 15);
                const int b   = gr >> 12;
                const int k   = gr & 4095;
                const int kt_i = k >> 6, k_in = k & 63;
#pragma unroll
                for (int n = 0; n < 4; ++n) {
                    const int gc0 = col0 + wc * 64 + n * 16 + (lane >> 4) * 4;
                    const int h   = gc0 >> 6, d0 = gc0 & 63;
                    u16* blob = KT + (((size_t)((b << 4) + h) * 64 + kt_i) << 9) * 8;
                    const int og = k_in * 8 + ((d0 >> 3) ^ (k_in & 7));
                    ushort4 pk;
                    pk.x = f2bf(acc[m][n][0]); pk.y = f2bf(acc[m][n][1]);
                    pk.z = f2bf(acc[m][n][2]); pk.w = f2bf(acc[m][n][3]);
                    *reinterpret_cast<ushort4*>(&blob[og * 8 + (d0 & 7)]) = pk;
                }
            }
        } else {
            for (int k0 = 0; k0 < 1024; k0 += 64) {
                stage(k0);
#pragma unroll
                for (int kk = 0; kk < 2; ++kk) {
                    bf16x8 af[4], bfr[4];
                    const int G = ((kk * 4 + (lane >> 4)) ^ x7) * 8;
#pragma unroll
                    for (int m = 0; m < 4; ++m)
                        af[m] = *reinterpret_cast<const bf16x8*>(
                            &As[(MROW + m * 16 + (lane & 15)) * 64 + G]);
#pragma unroll
                    for (int n = 0; n < 4; ++n)
                        bfr[n] = *reinterpret_cast<const bf16x8*>(
                            &Bs[(wc * 64 + n * 16 + (lane & 15)) * 64 + G]);
#pragma unroll
                    for (int m = 0; m < 4; ++m)
#pragma unroll
                        for (int n = 0; n < 4; ++n)
                            acc[m][n] = __builtin_amdgcn_mfma_f32_16x16x32_bf16(
                                af[m], bfr[n], acc[m][n], 0, 0, 0);
                }
            }
#pragma unroll
            for (int m = 0; m < 4; ++m) {
                const int gr0 = row0 + MROW + m * 16 + (lane >> 4) * 4;
                const int b   = gr0 >> 12;
                const int k   = gr0 & 4095;
                const int kt_i = k >> 6, k_in = k & 63;
#pragma unroll
                for (int n = 0; n < 4; ++n) {
                    const int gc = col0 + wc * 64 + n * 16 + (lane & 15);
                    const int h  = (gc & 1023) >> 6, d = gc & 63;
                    u16* blob = VT + (((size_t)((b << 4) + h) * 64 + kt_i) << 9) * 8;
                    const int og = d * 8 + ((k_in >> 3) ^ (d & 7));
                    ushort4 pk;
                    pk.x = f2bf(acc[m][n][0]); pk.y = f2bf(acc[m][n][1]);
                    pk.z = f2bf(acc[m][n][2]); pk.w = f2bf(acc[m][n][3]);
                    *reinterpret_cast<ushort4*>(&blob[og * 8 + (k_in & 7)]) = pk;
                }
            }
        }
    } else {
        const int id = blockIdx.x - 1024;
        const int sw = (id & 7) * 32 + (id >> 3);
        const int bx = sw % 8, by = sw / 8;
        const int row0 = by * 64, col0 = bx * 128;
        const int MROW = wr * 32;

        f32x4 acc[2][4];
#pragma unroll
        for (int m = 0; m < 2; ++m)
#pragma unroll
            for (int n = 0; n < 4; ++n) acc[m][n] = (f32x4){0.f, 0.f, 0.f, 0.f};

        for (int k0 = 0; k0 < 1024; k0 += 64) {
            __syncthreads();
#pragma unroll
            for (int p = 0; p < 2; ++p) {
                const int base = w * 512 + p * 2048;
                const int row  = (base >> 6) + lrow;
                gload16(Aq + (size_t)(row0 + row) * 1024 + k0 + swcol, &As[base]);
            }
#pragma unroll
            for (int p = 0; p < 4; ++p) {
                const int base = w * 512 + p * 2048;
                const int row  = (base >> 6) + lrow;
                gload16(wqT + (size_t)(col0 + row) * 1024 + k0 + lcol, &Bs[base]);
            }
            __syncthreads();
#pragma unroll
            for (int kk = 0; kk < 2; ++kk) {
                bf16x8 af[2], bfr[4];
                const int G = ((kk * 4 + (lane >> 4)) ^ x7) * 8;
#pragma unroll
                for (int m = 0; m < 2; ++m)
                    af[m] = *reinterpret_cast<const bf16x8*>(
                        &As[(MROW + m * 16 + (lane & 15)) * 64 + G]);
#pragma unroll
                for (int n = 0; n < 4; ++n)
                    bfr[n] = *reinterpret_cast<const bf16x8*>(
                        &Bs[(wc * 64 + n * 16 + (lane & 15)) * 64 + G]);
#pragma unroll
                for (int m = 0; m < 2; ++m)
#pragma unroll
                    for (int n = 0; n < 4; ++n)
                        acc[m][n] = __builtin_amdgcn_mfma_f32_16x16x32_bf16(
                            af[m], bfr[n], acc[m][n], 0, 0, 0);
            }
        }
#pragma unroll
        for (int m = 0; m < 2; ++m)
#pragma unroll
            for (int n = 0; n < 4; ++n) {
                const int gc = col0 + wc * 64 + n * 16 + (lane & 15);
#pragma unroll
                for (int r = 0; r < 4; ++r) {
                    const int gr = row0 + MROW + m * 16 + (lane >> 4) * 4 + r;
                    Qb[(size_t)gr * 1024 + gc] = f2bf(acc[m][n][r] * QSCALE);
                }
            }
    }
}

// ---------------------------------------------------------------------------
// Split-K bf16 flash attention — ROUND-13 PROVEN VERSION (74 us):
// 32x32x16 MFMA + in-register P via cvt_pk + permlane32_swap, KSPLIT=2.
// Grid: KSPLIT * B * NH * (QL/128) = 512 blocks, 256 threads.
// ---------------------------------------------------------------------------
__global__ __launch_bounds__(256, 2) void attn_mfma(const u16* __restrict__ Qb,
                                                    const u16* __restrict__ KT,
                                                    const u16* __restrict__ VT2,
                                                    float* __restrict__ Op,
                                                    float* __restrict__ m_ws,
                                                    float* __restrict__ l_ws) {
    __shared__ u16 Ks[2][4096];   // [key][slot*8], slot = gl ^ (key&7)
    __shared__ u16 Vs[2][4096];   // [d][slot*8],   slot = gl ^ (d&7)

    const int bid0 = blockIdx.x;
    const int bid  = (bid0 & 7) * 64 + (bid0 >> 3);   // XCD swizzle (512 blocks)
    const int qb   = bid & 7;
    const int h    = (bid >> 3) & 15;
    const int b    = (bid >> 7) & 1;
    const int c    = bid >> 8;
    const int tid  = threadIdx.x;
    const int lane = tid & 63;
    const int w    = tid >> 6;
    const int q    = lane & 31;       // this lane's q column
    const int hl   = lane >> 5;       // half (k-element group)
    const int l7   = lane & 7;
    const int q0   = qb * 128;
    const int bh   = b * NH + h;

    // Q B-frags: qa[dc](lane,e) = Q[q][d = dc*16 + hl*8 + e]
    bf16x8 qa[4];
    {
        const u16* qsrc = Qb + (size_t)(b * QL + q0 + w * 32 + q) * Hh
                          + h * HD + hl * 8;
#pragma unroll
        for (int dc = 0; dc < 4; ++dc)
            qa[dc] = *reinterpret_cast<const bf16x8*>(qsrc + dc * 16);
    }
    asm volatile("s_waitcnt vmcnt(0)" ::: "memory");

    float m_i = -1e30f, l_i = 0.f;
    f32x16 accO[2];
#pragma unroll
    for (int d2 = 0; d2 < 2; ++d2)
#pragma unroll
        for (int r = 0; r < 16; ++r) accO[d2][r] = 0.f;

    // hoisted LDS addressing
    const u16* Kb0 = &Ks[0][q * 64];
    const u16* Vb0 = &Vs[0][q * 64];
    int off[4];
#pragma unroll
    for (int j = 0; j < 4; ++j) off[j] = (((j * 2 + hl) ^ l7) << 3);

    // staging pointers
    const size_t tb0 = ((size_t)bh * 64 + c * NTT) * 4096;
    const u16* kpt = KT  + tb0 + (size_t)(w * 64 + lane) * 8 + 1024;
    const u16* vpt = VT2 + tb0 + (size_t)(w * 64 + lane) * 8 + 1024;
    u16* kdst[2] = { &Ks[0][w * 512], &Ks[1][w * 512] };
    u16* vdst[2] = { &Vs[0][w * 512], &Vs[1][w * 512] };

    gload16(kpt - 1024, kdst[0]);
    gload16(kpt + 1024, kdst[0] + 2048);
    gload16(vpt - 1024, vdst[0]);
    gload16(vpt + 1024, vdst[0] + 2048);

    auto tile = [&](int CUR, int t) {
        __builtin_amdgcn_s_barrier();
        if (t + 1 < NTT) {
            kpt += 4096; vpt += 4096;
            gload16(kpt - 1024, kdst[CUR ^ 1]);
            gload16(kpt + 1024, kdst[CUR ^ 1] + 2048);
            gload16(vpt - 1024, vdst[CUR ^ 1]);
            gload16(vpt + 1024, vdst[CUR ^ 1] + 2048);
            asm volatile("s_waitcnt vmcnt(4)" ::: "memory");
        } else {
            asm volatile("s_waitcnt vmcnt(0)" ::: "memory");
        }
        __builtin_amdgcn_sched_barrier(0);
        __builtin_amdgcn_s_barrier();

        // QK^T: sc[kc][reg] = S[key = kc*32 + (reg&3)+8*(reg>>2)+4*hl][q]
        f32x16 sc[2];
        __builtin_amdgcn_s_setprio(1);
#pragma unroll
        for (int kc = 0; kc < 2; ++kc) {
            f32x16 z;
#pragma unroll
            for (int r = 0; r < 16; ++r) z[r] = 0.f;
#pragma unroll
            for (int dc = 0; dc < 4; ++dc) {
                bf16x8 kf = *reinterpret_cast<const bf16x8*>(
                    Kb0 + CUR * 4096 + kc * 2048 + off[dc]);
                z = __builtin_amdgcn_mfma_f32_32x32x16_bf16(kf, qa[dc], z, 0, 0, 0);
            }
            sc[kc] = z;
        }
        __builtin_amdgcn_s_setprio(0);

        // max over this lane's 32 scores, then combine lane pair (xor 32)
        float mx = max3f(sc[0][0], sc[0][1], sc[0][2]);
#pragma unroll
        for (int i = 3; i + 1 < 32; i += 2)
            mx = max3f(mx, sc[i >> 4][i & 15], sc[(i + 1) >> 4][(i + 1) & 15]);
        mx = fmaxf(mx, sc[1][15]);
        mx = fmaxf(mx, __shfl_xor(mx, 32));

        if (__any(mx > m_i + RTHR)) {          // defer-max
            const float mnew = fmaxf(m_i, mx);
            const float al   = exp2f(m_i - mnew);
            m_i = mnew;
            l_i *= al;
#pragma unroll
            for (int d2 = 0; d2 < 2; ++d2)
#pragma unroll
                for (int r = 0; r < 16; ++r) accO[d2][r] *= al;
        }
#pragma unroll
        for (int kc = 0; kc < 2; ++kc)
#pragma unroll
            for (int r = 0; r < 16; ++r) sc[kc][r] = exp2f(sc[kc][r] - m_i);

        // l: in-lane pairwise sum + cross-half shfl
        {
            float p0 = sc[0][0], p1 = sc[0][1], p2 = sc[0][2], p3 = sc[0][3];
#pragma unroll
            for (int i = 4; i < 16; i += 4) {
                p0 += sc[0][i];     p1 += sc[0][i + 1];
                p2 += sc[0][i + 2]; p3 += sc[0][i + 3];
            }
#pragma unroll
            for (int i = 0; i < 16; i += 4) {
                p0 += sc[1][i];     p1 += sc[1][i + 1];
                p2 += sc[1][i + 2]; p3 += sc[1][i + 3];
            }
            float sum = (p0 + p1) + (p2 + p3);
            sum += __shfl_xor(sum, 32);
            l_i += sum;
        }

        // PV: per k-chunk kk, build P B-frag in registers via permlane32_swap
        __builtin_amdgcn_s_setprio(1);
#pragma unroll
        for (int kk = 0; kk < 4; ++kk) {
            const int kc  = kk >> 1;
            const int rb  = (kk & 1) * 8;
            unsigned int X0 = cvt_pk_bf16(sc[kc][rb + 0], sc[kc][rb + 1]);
            unsigned int X1 = cvt_pk_bf16(sc[kc][rb + 2], sc[kc][rb + 3]);
            unsigned int Y0 = cvt_pk_bf16(sc[kc][rb + 4], sc[kc][rb + 5]);
            unsigned int Y1 = cvt_pk_bf16(sc[kc][rb + 6], sc[kc][rb + 7]);
            plane32swap(X0, Y0);
            plane32swap(X1, Y1);
            uint4 wv = make_uint4(X0, X1, Y0, Y1);
            bf16x8 pf;
            __builtin_memcpy(&pf, &wv, 16);
            bf16x8 vf0 = *reinterpret_cast<const bf16x8*>(
                Vb0 + CUR * 4096 + off[kk]);
            bf16x8 vf1 = *reinterpret_cast<const bf16x8*>(
                Vb0 + CUR * 4096 + 2048 + off[kk]);
            accO[0] = __builtin_amdgcn_mfma_f32_32x32x16_bf16(vf0, pf, accO[0], 0, 0, 0);
            accO[1] = __builtin_amdgcn_mfma_f32_32x32x16_bf16(vf1, pf, accO[1], 0, 0, 0);
        }
        __builtin_amdgcn_s_setprio(0);
    };

    for (int t = 0; t < NTT; t += 2) {
        tile(0, t);
        tile(1, t + 1);
    }

    // epilogue: unnormalized O (float4 stores) + per-row m,l
    float* opc = Op + (size_t)c * ((size_t)Bb * QL * Hh)
                 + (size_t)(b * QL + q0 + w * 32 + q) * Hh + h * HD;
#pragma unroll
    for (int d2 = 0; d2 < 2; ++d2) {
#pragma unroll
        for (int b2 = 0; b2 < 4; ++b2) {
            float4 v = make_float4(accO[d2][4 * b2 + 0], accO[d2][4 * b2 + 1],
                                   accO[d2][4 * b2 + 2], accO[d2][4 * b2 + 3]);
            *reinterpret_cast<float4*>(opc + d2 * 32 + b2 * 8 + hl * 4) = v;
        }
    }
    if (hl == 0) {
        const int idx = ((c * Bb + b) * NH + h) * QL + q0 + w * 32 + q;
        m_ws[idx] = m_i;
        l_ws[idx] = l_i;
    }
}

// ---------------------------------------------------------------------------
// Combine KSPLIT=2 partials -> bf16 AO [B*QL][1024]  (log2-domain maxima)
// ---------------------------------------------------------------------------
__global__ __launch_bounds__(256) void attn_combine(const float* __restrict__ Op,
                                                    const float* __restrict__ m_ws,
                                                    const float* __restrict__ l_ws,
                                                    u16* __restrict__ AO) {
    const int id  = blockIdx.x * 256 + threadIdx.x;
    const int e0  = id * 4;
    const int row = e0 >> 10;
    const int col = e0 & 1023;
    const int b   = row >> 10;
    const int q   = row & 1023;
    const int hh  = col >> 6;
    const int i0  = ((b << 4) + hh) * 1024 + q;
    const int i1  = i0 + 32768;
    const float m0 = m_ws[i0], m1 = m_ws[i1];
    const float l0 = l_ws[i0], l1 = l_ws[i1];
    const float ms = fmaxf(m0, m1);
    const float w0 = exp2f(m0 - ms), w1 = exp2f(m1 - ms);
    const float inv = 1.f / (l0 * w0 + l1 * w1);
    const size_t off = (size_t)row * 1024 + col;
    float4 o0 = *reinterpret_cast<const float4*>(Op + off);
    float4 o1 = *reinterpret_cast<const float4*>(Op + (size_t)Bb * QL * Hh + off);
    ushort4 o;
    o.x = f2bf((o0.x * w0 + o1.x * w1) * inv);
    o.y = f2bf((o0.y * w0 + o1.y * w1) * inv);
    o.z = f2bf((o0.z * w0 + o1.z * w1) * inv);
    o.w = f2bf((o0.w * w0 + o1.w * w1) * inv);
    *reinterpret_cast<ushort4*>(AO + off) = o;
}

// ---------------------------------------------------------------------------
// Output GEMM — pure m97 structure (same as qkvgemm Q path): bf16 AO via
// gload16 with per-lane XOR'd source granule, pre-swizzled woutT, f32 out.
// ---------------------------------------------------------------------------
__global__ __launch_bounds__(256) void ogemm(const u16* __restrict__ AO,
                                             const u16* __restrict__ Bt,
                                             float* __restrict__ C) {
    __shared__ u16 As[64 * 64];
    __shared__ u16 Bs[128 * 64];
    const int nwg = gridDim.x * gridDim.y;
    const int id  = blockIdx.y * gridDim.x + blockIdx.x;
    const int sw  = (id & 7) * (nwg >> 3) + (id >> 3);
    const int bx  = sw % gridDim.x, by = sw / gridDim.x;
    const int tid = threadIdx.x, lane = tid & 63, w = tid >> 6;
    const int wr = w >> 1, wc = w & 1;
    const int row0 = by * 64, col0 = bx * 128;
    const int MROW = wr * 32;
    const int x7   = lane & 7;
    const int lrow = lane >> 3, lcol = (lane & 7) * 8;
    const int swcol = lcol ^ ((lrow & 7) << 3);

    f32x4 acc[2][4];
#pragma unroll
    for (int m = 0; m < 2; ++m)
#pragma unroll
        for (int n = 0; n < 4; ++n) acc[m][n] = (f32x4){0.f, 0.f, 0.f, 0.f};

    for (int k0 = 0; k0 < 1024; k0 += 64) {
        __syncthreads();
#pragma unroll
        for (int p = 0; p < 2; ++p) {
            const int base = w * 512 + p * 2048;
            const int row  = (base >> 6) + lrow;
            gload16(AO + (size_t)(row0 + row) * 1024 + k0 + swcol, &As[base]);
        }
#pragma unroll
        for (int p = 0; p < 4; ++p) {
            const int base = w * 512 + p * 2048;
            const int row  = (base >> 6) + lrow;
            gload16(Bt + (size_t)(col0 + row) * 1024 + k0 + lcol, &Bs[base]);
        }
        __syncthreads();
#pragma unroll
        for (int kk = 0; kk < 2; ++kk) {
            bf16x8 af[2], bfr[4];
            const int G = ((kk * 4 + (lane >> 4)) ^ x7) * 8;
#pragma unroll
            for (int m = 0; m < 2; ++m)
                af[m] = *reinterpret_cast<const bf16x8*>(
                    &As[(MROW + m * 16 + (lane & 15)) * 64 + G]);
#pragma unroll
            for (int n = 0; n < 4; ++n)
                bfr[n] = *reinterpret_cast<const bf16x8*>(
                    &Bs[(wc * 64 + n * 16 + (lane & 15)) * 64 + G]);
#pragma unroll
            for (int m = 0; m < 2; ++m)
#pragma unroll
                for (int n = 0; n < 4; ++n)
                    acc[m][n] = __builtin_amdgcn_mfma_f32_16x16x32_bf16(
                        af[m], bfr[n], acc[m][n], 0, 0, 0);
        }
    }
#pragma unroll
    for (int m = 0; m < 2; ++m)
#pragma unroll
        for (int n = 0; n < 4; ++n) {
            const int gc = col0 + wc * 64 + n * 16 + (lane & 15);
#pragma unroll
            for (int r = 0; r < 4; ++r) {
                const int gr = row0 + MROW + m * 16 + (lane >> 4) * 4 + r;
                C[(size_t)gr * 1024 + gc] = acc[m][n][r];
            }
        }
}

// ---------------------------------------------------------------------------
// Launch.  Workspace (ws >= 80 MB):
//   0-16 KT | 16-32 VT | 32-48 kvbf -> Opart[2] | 48-52 Qb | 52-56 wkvT
//  56-58 wqT | 58-60 woutT | 60-60.5 m_ws,l_ws | 64-68 qbf -> AO
// ---------------------------------------------------------------------------
extern "C" void kernel_launch(void* const* d_in, const int* in_sizes, int n_in,
                              void* d_out, int out_size, void* d_ws, size_t ws_size,
                              hipStream_t stream) {
    const float* query     = (const float*)d_in[0];
    const float* key_value = (const float*)d_in[1];
    const float* w_q       = (const float*)d_in[2];
    const float* w_kv      = (const float*)d_in[3];
    const float* w_out     = (const float*)d_in[4];
    float* out = (float*)d_out;

    char* ws = (char*)d_ws;
    const size_t MB = 1024 * 1024;
    u16*   KT    = (u16*)(ws);
    u16*   VT    = (u16*)(ws + 16 * MB);
    u16*   kvbf  = (u16*)(ws + 32 * MB);   // dead after qkvgemm
    float* Opart = (float*)(ws + 32 * MB); // written by attn
    u16*   Qb    = (u16*)(ws + 48 * MB);
    u16*   wkvT  = (u16*)(ws + 52 * MB);
    u16*   wqT   = (u16*)(ws + 56 * MB);
    u16*   woutT = (u16*)(ws + 58 * MB);
    float* m_wsp = (float*)(ws + 60 * MB);
    float* l_wsp = (float*)(ws + 60 * MB + 256 * 1024);
    u16*   qbf   = (u16*)(ws + 64 * MB);   // dead after qkvgemm
    u16*   AO    = (u16*)(ws + 64 * MB);   // written by combine

    dim3 blk(256);

    // 1) weight transposes (swizzled) + activation casts, one launch
    prep_all<<<6144, blk, 0, stream>>>(w_q, w_kv, w_out, query, key_value,
                                       wqT, wkvT, woutT, qbf, kvbf);

    // 2) FUSED Q + KV projections (m97 structure)
    qkvgemm<<<1280, blk, 0, stream>>>(qbf, kvbf, wqT, wkvT, Qb, KT, VT);

    // 3) split-K flash attention (R13 proven: 32x32 MFMA, in-register P)
    attn_mfma<<<dim3(KSPLIT * 256), blk, 0, stream>>>(
        Qb, KT, VT, Opart, m_wsp, l_wsp);

    // 4) combine partials -> bf16 AO (read Opart once, not 8x)
    attn_combine<<<2048, blk, 0, stream>>>(Opart, m_wsp, l_wsp, AO);

    // 5) output GEMM (pure m97, gload16 A staging)
    ogemm<<<dim3(8, 32), blk, 0, stream>>>(AO, woutT, out);
}

// Round 16
// 150.314 us; speedup vs baseline: 1.2879x; 1.0018x over previous
//
#include <hip/hip_runtime.h>

// Problem constants (CompactCrossAttention)
#define Bb   2
#define QL   1024
#define KL   4096
#define Hh   1024
#define NH   16
#define HD   64

#define KSPLIT 2
#define CHUNK  (KL / KSPLIT)   // 2048 keys per block
#define NTT    (CHUNK / 64)    // 32 tiles of 64 keys

typedef unsigned short u16;
typedef __attribute__((ext_vector_type(8))) short bf16x8;     // MFMA A/B frag
typedef __attribute__((ext_vector_type(4))) float f32x4;      // 16x16 C/D frag
typedef __attribute__((ext_vector_type(16))) float f32x16;    // 32x32 C/D frag

#define QSCALE 0.1803368801111204f   // 0.125 * log2(e): scores in log2 domain
#define RTHR   11.0f                 // defer-max threshold (log2 units)

__device__ __forceinline__ u16 f2bf(float f) {
    union { float f; unsigned int u; } v; v.f = f;
    unsigned int r = (v.u + 0x7FFFu + ((v.u >> 16) & 1u)) >> 16;
    return (u16)r;
}

__device__ __forceinline__ unsigned int cvt_pk_bf16(float lo, float hi) {
    unsigned int r;
    asm("v_cvt_pk_bf16_f32 %0, %1, %2" : "=v"(r) : "v"(lo), "v"(hi));
    return r;
}

__device__ __forceinline__ float max3f(float a, float b, float c) {
    float r;
    asm("v_max3_f32 %0, %1, %2, %3" : "=v"(r) : "v"(a), "v"(b), "v"(c));
    return r;
}

// v_permlane32_swap_b32: new_a[l<32]=a[l], new_a[l>=32]=b[l-32];
//                        new_b[l<32]=a[l+32], new_b[l>=32]=b[l]
__device__ __forceinline__ void plane32swap(unsigned int& a, unsigned int& b) {
    asm volatile("v_permlane32_swap_b32 %0, %1" : "+v"(a), "+v"(b));
}

__device__ __forceinline__ void gload16(const void* g, void* l) {
    __builtin_amdgcn_global_load_lds(
        (const __attribute__((address_space(1))) void*)g,
        (__attribute__((address_space(3))) void*)l, 16, 0, 0);
}

// pack 8 fp32 -> 8 bf16 (uint4)
__device__ __forceinline__ uint4 pack8(const float4& f0, const float4& f1) {
    uint4 o;
    o.x = cvt_pk_bf16(f0.x, f0.y);
    o.y = cvt_pk_bf16(f0.z, f0.w);
    o.z = cvt_pk_bf16(f1.x, f1.y);
    o.w = cvt_pk_bf16(f1.z, f1.w);
    return o;
}

// ---------------------------------------------------------------------------
// PREP: weight transposes (swizzled) + activation casts, ONE launch.
// ---------------------------------------------------------------------------
__global__ __launch_bounds__(256) void prep_all(const float* __restrict__ wq,
                                                const float* __restrict__ wkv,
                                                const float* __restrict__ wout,
                                                const float* __restrict__ qact,
                                                const float* __restrict__ kvact,
                                                u16* __restrict__ wqT,
                                                u16* __restrict__ wkvT,
                                                u16* __restrict__ woutT,
                                                u16* __restrict__ qb,
                                                u16* __restrict__ kvb) {
    __shared__ float T[64][65];
    int bid = blockIdx.x;
    if (bid >= 1024) {
        bid -= 1024;
        const float* in; u16* out;
        if (bid < 1024) { in = qact;  out = qb;  }
        else            { in = kvact; out = kvb; bid -= 1024; }
        const size_t i = ((size_t)bid * 256 + threadIdx.x) * 8;
        float4 f0 = *reinterpret_cast<const float4*>(in + i);
        float4 f1 = *reinterpret_cast<const float4*>(in + i + 4);
        *reinterpret_cast<uint4*>(out + i) = pack8(f0, f1);
        return;
    }
    const float* in; u16* out; int C;
    if (bid < 256)      { in = wq;   out = wqT;   C = 1024; }
    else if (bid < 768) { in = wkv;  out = wkvT;  C = 2048; bid -= 256; }
    else                { in = wout; out = woutT; C = 1024; bid -= 768; }
    const int nc = C >> 6;
    const int c0 = (bid % nc) * 64;
    const int r0 = (bid / nc) * 64;
    const int t  = threadIdx.x;
    const int tx = t & 15, ty = t >> 4;
#pragma unroll
    for (int p = 0; p < 4; ++p) {
        const int r = ty + p * 16;
        float4 v = *reinterpret_cast<const float4*>(in + (size_t)(r0 + r) * C + c0 + tx * 4);
        T[r][tx * 4 + 0] = v.x; T[r][tx * 4 + 1] = v.y;
        T[r][tx * 4 + 2] = v.z; T[r][tx * 4 + 3] = v.w;
    }
    __syncthreads();
#pragma unroll
    for (int p = 0; p < 4; ++p) {
        const int c = ty + p * 16;
        const int n = c0 + c;
        ushort4 o;
        o.x = f2bf(T[tx * 4 + 0][c]); o.y = f2bf(T[tx * 4 + 1][c]);
        o.z = f2bf(T[tx * 4 + 2][c]); o.w = f2bf(T[tx * 4 + 3][c]);
        const int kb   = r0 + tx * 4;
        const int kout = (kb & ~63) | ((((kb >> 3) & 7) ^ (n & 7)) << 3) | (kb & 7);
        *reinterpret_cast<ushort4*>(out + (size_t)n * 1024 + kout) = o;
    }
}

// ---------------------------------------------------------------------------
// FUSED Q + KV projection GEMM — m97 structure (unchanged from round 12).
// ---------------------------------------------------------------------------
__global__ __launch_bounds__(256) void qkvgemm(const u16* __restrict__ Aq,
                                               const u16* __restrict__ Akv,
                                               const u16* __restrict__ wqT,
                                               const u16* __restrict__ wkvT,
                                               u16* __restrict__ Qb,
                                               u16* __restrict__ KT,
                                               u16* __restrict__ VT) {
    __shared__ u16 As[128 * 64];
    __shared__ u16 Bs[128 * 64];
    const int tid = threadIdx.x, lane = tid & 63, w = tid >> 6;
    const int wr = w >> 1, wc = w & 1;
    const int x7 = lane & 7;
    const int lrow = lane >> 3, lcol = (lane & 7) * 8;
    const int swcol = lcol ^ ((lrow & 7) << 3);   // A source granule XOR

    if (blockIdx.x < 1024) {
        const int id = blockIdx.x;
        const int sw = (id & 7) * 128 + (id >> 3);
        const int bx = sw % 16, by = sw / 16;
        const int row0 = by * 128, col0 = bx * 128;
        const int MROW = wr * 64;

        f32x4 acc[4][4];
#pragma unroll
        for (int m = 0; m < 4; ++m)
#pragma unroll
            for (int n = 0; n < 4; ++n) acc[m][n] = (f32x4){0.f, 0.f, 0.f, 0.f};

        auto stage = [&](int k0) {
            __syncthreads();
#pragma unroll
            for (int p = 0; p < 4; ++p) {
                const int base = w * 512 + p * 2048;
                const int row  = (base >> 6) + lrow;
                gload16(Akv + (size_t)(row0 + row) * 1024 + k0 + swcol, &As[base]);
                gload16(wkvT + (size_t)(col0 + row) * 1024 + k0 + lcol, &Bs[base]);
            }
            __syncthreads();
        };

        if (col0 < 1024) {
            for (int k0 = 0; k0 < 1024; k0 += 64) {
                stage(k0);
#pragma unroll
                for (int kk = 0; kk < 2; ++kk) {
                    bf16x8 af[4], bfr[4];
                    const int G = ((kk * 4 + (lane >> 4)) ^ x7) * 8;
#pragma unroll
                    for (int m = 0; m < 4; ++m)
                        af[m] = *reinterpret_cast<const bf16x8*>(
                            &As[(MROW + m * 16 + (lane & 15)) * 64 + G]);
#pragma unroll
                    for (int n = 0; n < 4; ++n)
                        bfr[n] = *reinterpret_cast<const bf16x8*>(
                            &Bs[(wc * 64 + n * 16 + (lane & 15)) * 64 + G]);
#pragma unroll
                    for (int m = 0; m < 4; ++m)
#pragma unroll
                        for (int n = 0; n < 4; ++n)
                            acc[m][n] = __builtin_amdgcn_mfma_f32_16x16x32_bf16(
                                bfr[n], af[m], acc[m][n], 0, 0, 0);
                }
            }
#pragma unroll
            for (int m = 0; m < 4; ++m) {
                const int gr  = row0 + MROW + m * 16 + (lane & 15);
                const int b   = gr >> 12;
                const int k   = gr & 4095;
                const int kt_i = k >> 6, k_in = k & 63;
#pragma unroll
                for (int n = 0; n < 4; ++n) {
                    const int gc0 = col0 + wc * 64 + n * 16 + (lane >> 4) * 4;
                    const int h   = gc0 >> 6, d0 = gc0 & 63;
                    u16* blob = KT + (((size_t)((b << 4) + h) * 64 + kt_i) << 9) * 8;
                    const int og = k_in * 8 + ((d0 >> 3) ^ (k_in & 7));
                    ushort4 pk;
                    pk.x = f2bf(acc[m][n][0]); pk.y = f2bf(acc[m][n][1]);
                    pk.z = f2bf(acc[m][n][2]); pk.w = f2bf(acc[m][n][3]);
                    *reinterpret_cast<ushort4*>(&blob[og * 8 + (d0 & 7)]) = pk;
                }
            }
        } else {
            for (int k0 = 0; k0 < 1024; k0 += 64) {
                stage(k0);
#pragma unroll
                for (int kk = 0; kk < 2; ++kk) {
                    bf16x8 af[4], bfr[4];
                    const int G = ((kk * 4 + (lane >> 4)) ^ x7) * 8;
#pragma unroll
                    for (int m = 0; m < 4; ++m)
                        af[m] = *reinterpret_cast<const bf16x8*>(
                            &As[(MROW + m * 16 + (lane & 15)) * 64 + G]);
#pragma unroll
                    for (int n = 0; n < 4; ++n)
                        bfr[n] = *reinterpret_cast<const bf16x8*>(
                            &Bs[(wc * 64 + n * 16 + (lane & 15)) * 64 + G]);
#pragma unroll
                    for (int m = 0; m < 4; ++m)
#pragma unroll
                        for (int n = 0; n < 4; ++n)
                            acc[m][n] = __builtin_amdgcn_mfma_f32_16x16x32_bf16(
                                af[m], bfr[n], acc[m][n], 0, 0, 0);
                }
            }
#pragma unroll
            for (int m = 0; m < 4; ++m) {
                const int gr0 = row0 + MROW + m * 16 + (lane >> 4) * 4;
                const int b   = gr0 >> 12;
                const int k   = gr0 & 4095;
                const int kt_i = k >> 6, k_in = k & 63;
#pragma unroll
                for (int n = 0; n < 4; ++n) {
                    const int gc = col0 + wc * 64 + n * 16 + (lane & 15);
                    const int h  = (gc & 1023) >> 6, d = gc & 63;
                    u16* blob = VT + (((size_t)((b << 4) + h) * 64 + kt_i) << 9) * 8;
                    const int og = d * 8 + ((k_in >> 3) ^ (d & 7));
                    ushort4 pk;
                    pk.x = f2bf(acc[m][n][0]); pk.y = f2bf(acc[m][n][1]);
                    pk.z = f2bf(acc[m][n][2]); pk.w = f2bf(acc[m][n][3]);
                    *reinterpret_cast<ushort4*>(&blob[og * 8 + (k_in & 7)]) = pk;
                }
            }
        }
    } else {
        const int id = blockIdx.x - 1024;
        const int sw = (id & 7) * 32 + (id >> 3);
        const int bx = sw % 8, by = sw / 8;
        const int row0 = by * 64, col0 = bx * 128;
        const int MROW = wr * 32;

        f32x4 acc[2][4];
#pragma unroll
        for (int m = 0; m < 2; ++m)
#pragma unroll
            for (int n = 0; n < 4; ++n) acc[m][n] = (f32x4){0.f, 0.f, 0.f, 0.f};

        for (int k0 = 0; k0 < 1024; k0 += 64) {
            __syncthreads();
#pragma unroll
            for (int p = 0; p < 2; ++p) {
                const int base = w * 512 + p * 2048;
                const int row  = (base >> 6) + lrow;
                gload16(Aq + (size_t)(row0 + row) * 1024 + k0 + swcol, &As[base]);
            }
#pragma unroll
            for (int p = 0; p < 4; ++p) {
                const int base = w * 512 + p * 2048;
                const int row  = (base >> 6) + lrow;
                gload16(wqT + (size_t)(col0 + row) * 1024 + k0 + lcol, &Bs[base]);
            }
            __syncthreads();
#pragma unroll
            for (int kk = 0; kk < 2; ++kk) {
                bf16x8 af[2], bfr[4];
                const int G = ((kk * 4 + (lane >> 4)) ^ x7) * 8;
#pragma unroll
                for (int m = 0; m < 2; ++m)
                    af[m] = *reinterpret_cast<const bf16x8*>(
                        &As[(MROW + m * 16 + (lane & 15)) * 64 + G]);
#pragma unroll
                for (int n = 0; n < 4; ++n)
                    bfr[n] = *reinterpret_cast<const bf16x8*>(
                        &Bs[(wc * 64 + n * 16 + (lane & 15)) * 64 + G]);
#pragma unroll
                for (int m = 0; m < 2; ++m)
#pragma unroll
                    for (int n = 0; n < 4; ++n)
                        acc[m][n] = __builtin_amdgcn_mfma_f32_16x16x32_bf16(
                            af[m], bfr[n], acc[m][n], 0, 0, 0);
            }
        }
#pragma unroll
        for (int m = 0; m < 2; ++m)
#pragma unroll
            for (int n = 0; n < 4; ++n) {
                const int gc = col0 + wc * 64 + n * 16 + (lane & 15);
#pragma unroll
                for (int r = 0; r < 4; ++r) {
                    const int gr = row0 + MROW + m * 16 + (lane >> 4) * 4 + r;
                    Qb[(size_t)gr * 1024 + gc] = f2bf(acc[m][n][r] * QSCALE);
                }
            }
    }
}

// ---------------------------------------------------------------------------
// Split-K bf16 flash attention — ROUND-13 PROVEN VERSION (74 us):
// 32x32x16 MFMA + in-register P via cvt_pk + permlane32_swap, KSPLIT=2.
// Grid: KSPLIT * B * NH * (QL/128) = 512 blocks, 256 threads.
// ---------------------------------------------------------------------------
__global__ __launch_bounds__(256, 2) void attn_mfma(const u16* __restrict__ Qb,
                                                    const u16* __restrict__ KT,
                                                    const u16* __restrict__ VT2,
                                                    float* __restrict__ Op,
                                                    float* __restrict__ m_ws,
                                                    float* __restrict__ l_ws) {
    __shared__ u16 Ks[2][4096];   // [key][slot*8], slot = gl ^ (key&7)
    __shared__ u16 Vs[2][4096];   // [d][slot*8],   slot = gl ^ (d&7)

    const int bid0 = blockIdx.x;
    const int bid  = (bid0 & 7) * 64 + (bid0 >> 3);   // XCD swizzle (512 blocks)
    const int qb   = bid & 7;
    const int h    = (bid >> 3) & 15;
    const int b    = (bid >> 7) & 1;
    const int c    = bid >> 8;
    const int tid  = threadIdx.x;
    const int lane = tid & 63;
    const int w    = tid >> 6;
    const int q    = lane & 31;       // this lane's q column
    const int hl   = lane >> 5;       // half (k-element group)
    const int l7   = lane & 7;
    const int q0   = qb * 128;
    const int bh   = b * NH + h;

    // Q B-frags: qa[dc](lane,e) = Q[q][d = dc*16 + hl*8 + e]
    bf16x8 qa[4];
    {
        const u16* qsrc = Qb + (size_t)(b * QL + q0 + w * 32 + q) * Hh
                          + h * HD + hl * 8;
#pragma unroll
        for (int dc = 0; dc < 4; ++dc)
            qa[dc] = *reinterpret_cast<const bf16x8*>(qsrc + dc * 16);
    }
    asm volatile("s_waitcnt vmcnt(0)" ::: "memory");

    float m_i = -1e30f, l_i = 0.f;
    f32x16 accO[2];
#pragma unroll
    for (int d2 = 0; d2 < 2; ++d2)
#pragma unroll
        for (int r = 0; r < 16; ++r) accO[d2][r] = 0.f;

    // hoisted LDS addressing
    const u16* Kb0 = &Ks[0][q * 64];
    const u16* Vb0 = &Vs[0][q * 64];
    int off[4];
#pragma unroll
    for (int j = 0; j < 4; ++j) off[j] = (((j * 2 + hl) ^ l7) << 3);

    // staging pointers
    const size_t tb0 = ((size_t)bh * 64 + c * NTT) * 4096;
    const u16* kpt = KT  + tb0 + (size_t)(w * 64 + lane) * 8 + 1024;
    const u16* vpt = VT2 + tb0 + (size_t)(w * 64 + lane) * 8 + 1024;
    u16* kdst[2] = { &Ks[0][w * 512], &Ks[1][w * 512] };
    u16* vdst[2] = { &Vs[0][w * 512], &Vs[1][w * 512] };

    gload16(kpt - 1024, kdst[0]);
    gload16(kpt + 1024, kdst[0] + 2048);
    gload16(vpt - 1024, vdst[0]);
    gload16(vpt + 1024, vdst[0] + 2048);

    auto tile = [&](int CUR, int t) {
        __builtin_amdgcn_s_barrier();
        if (t + 1 < NTT) {
            kpt += 4096; vpt += 4096;
            gload16(kpt - 1024, kdst[CUR ^ 1]);
            gload16(kpt + 1024, kdst[CUR ^ 1] + 2048);
            gload16(vpt - 1024, vdst[CUR ^ 1]);
            gload16(vpt + 1024, vdst[CUR ^ 1] + 2048);
            asm volatile("s_waitcnt vmcnt(4)" ::: "memory");
        } else {
            asm volatile("s_waitcnt vmcnt(0)" ::: "memory");
        }
        __builtin_amdgcn_sched_barrier(0);
        __builtin_amdgcn_s_barrier();

        // QK^T: sc[kc][reg] = S[key = kc*32 + (reg&3)+8*(reg>>2)+4*hl][q]
        f32x16 sc[2];
        __builtin_amdgcn_s_setprio(1);
#pragma unroll
        for (int kc = 0; kc < 2; ++kc) {
            f32x16 z;
#pragma unroll
            for (int r = 0; r < 16; ++r) z[r] = 0.f;
#pragma unroll
            for (int dc = 0; dc < 4; ++dc) {
                bf16x8 kf = *reinterpret_cast<const bf16x8*>(
                    Kb0 + CUR * 4096 + kc * 2048 + off[dc]);
                z = __builtin_amdgcn_mfma_f32_32x32x16_bf16(kf, qa[dc], z, 0, 0, 0);
            }
            sc[kc] = z;
        }
        __builtin_amdgcn_s_setprio(0);

        // max over this lane's 32 scores, then combine lane pair (xor 32)
        float mx = max3f(sc[0][0], sc[0][1], sc[0][2]);
#pragma unroll
        for (int i = 3; i + 1 < 32; i += 2)
            mx = max3f(mx, sc[i >> 4][i & 15], sc[(i + 1) >> 4][(i + 1) & 15]);
        mx = fmaxf(mx, sc[1][15]);
        mx = fmaxf(mx, __shfl_xor(mx, 32));

        if (__any(mx > m_i + RTHR)) {          // defer-max
            const float mnew = fmaxf(m_i, mx);
            const float al   = exp2f(m_i - mnew);
            m_i = mnew;
            l_i *= al;
#pragma unroll
            for (int d2 = 0; d2 < 2; ++d2)
#pragma unroll
                for (int r = 0; r < 16; ++r) accO[d2][r] *= al;
        }
#pragma unroll
        for (int kc = 0; kc < 2; ++kc)
#pragma unroll
            for (int r = 0; r < 16; ++r) sc[kc][r] = exp2f(sc[kc][r] - m_i);

        // l: in-lane pairwise sum + cross-half shfl
        {
            float p0 = sc[0][0], p1 = sc[0][1], p2 = sc[0][2], p3 = sc[0][3];
#pragma unroll
            for (int i = 4; i < 16; i += 4) {
                p0 += sc[0][i];     p1 += sc[0][i + 1];
                p2 += sc[0][i + 2]; p3 += sc[0][i + 3];
            }
#pragma unroll
            for (int i = 0; i < 16; i += 4) {
                p0 += sc[1][i];     p1 += sc[1][i + 1];
                p2 += sc[1][i + 2]; p3 += sc[1][i + 3];
            }
            float sum = (p0 + p1) + (p2 + p3);
            sum += __shfl_xor(sum, 32);
            l_i += sum;
        }

        // PV: per k-chunk kk, build P B-frag in registers via permlane32_swap
        __builtin_amdgcn_s_setprio(1);
#pragma unroll
        for (int kk = 0; kk < 4; ++kk) {
            const int kc  = kk >> 1;
            const int rb  = (kk & 1) * 8;
            unsigned int X0 = cvt_pk_bf16(sc[kc][rb + 0], sc[kc][rb + 1]);
            unsigned int X1 = cvt_pk_bf16(sc[kc][rb + 2], sc[kc][rb + 3]);
            unsigned int Y0 = cvt_pk_bf16(sc[kc][rb + 4], sc[kc][rb + 5]);
            unsigned int Y1 = cvt_pk_bf16(sc[kc][rb + 6], sc[kc][rb + 7]);
            plane32swap(X0, Y0);
            plane32swap(X1, Y1);
            uint4 wv = make_uint4(X0, X1, Y0, Y1);
            bf16x8 pf;
            __builtin_memcpy(&pf, &wv, 16);
            bf16x8 vf0 = *reinterpret_cast<const bf16x8*>(
                Vb0 + CUR * 4096 + off[kk]);
            bf16x8 vf1 = *reinterpret_cast<const bf16x8*>(
                Vb0 + CUR * 4096 + 2048 + off[kk]);
            accO[0] = __builtin_amdgcn_mfma_f32_32x32x16_bf16(vf0, pf, accO[0], 0, 0, 0);
            accO[1] = __builtin_amdgcn_mfma_f32_32x32x16_bf16(vf1, pf, accO[1], 0, 0, 0);
        }
        __builtin_amdgcn_s_setprio(0);
    };

    for (int t = 0; t < NTT; t += 2) {
        tile(0, t);
        tile(1, t + 1);
    }

    // epilogue: unnormalized O (float4 stores) + per-row m,l
    float* opc = Op + (size_t)c * ((size_t)Bb * QL * Hh)
                 + (size_t)(b * QL + q0 + w * 32 + q) * Hh + h * HD;
#pragma unroll
    for (int d2 = 0; d2 < 2; ++d2) {
#pragma unroll
        for (int b2 = 0; b2 < 4; ++b2) {
            float4 v = make_float4(accO[d2][4 * b2 + 0], accO[d2][4 * b2 + 1],
                                   accO[d2][4 * b2 + 2], accO[d2][4 * b2 + 3]);
            *reinterpret_cast<float4*>(opc + d2 * 32 + b2 * 8 + hl * 4) = v;
        }
    }
    if (hl == 0) {
        const int idx = ((c * Bb + b) * NH + h) * QL + q0 + w * 32 + q;
        m_ws[idx] = m_i;
        l_ws[idx] = l_i;
    }
}

// ---------------------------------------------------------------------------
// Combine KSPLIT=2 partials -> bf16 AO [B*QL][1024]  (log2-domain maxima)
// ---------------------------------------------------------------------------
__global__ __launch_bounds__(256) void attn_combine(const float* __restrict__ Op,
                                                    const float* __restrict__ m_ws,
                                                    const float* __restrict__ l_ws,
                                                    u16* __restrict__ AO) {
    const int id  = blockIdx.x * 256 + threadIdx.x;
    const int e0  = id * 4;
    const int row = e0 >> 10;
    const int col = e0 & 1023;
    const int b   = row >> 10;
    const int q   = row & 1023;
    const int hh  = col >> 6;
    const int i0  = ((b << 4) + hh) * 1024 + q;
    const int i1  = i0 + 32768;
    const float m0 = m_ws[i0], m1 = m_ws[i1];
    const float l0 = l_ws[i0], l1 = l_ws[i1];
    const float ms = fmaxf(m0, m1);
    const float w0 = exp2f(m0 - ms), w1 = exp2f(m1 - ms);
    const float inv = 1.f / (l0 * w0 + l1 * w1);
    const size_t off = (size_t)row * 1024 + col;
    float4 o0 = *reinterpret_cast<const float4*>(Op + off);
    float4 o1 = *reinterpret_cast<const float4*>(Op + (size_t)Bb * QL * Hh + off);
    ushort4 o;
    o.x = f2bf((o0.x * w0 + o1.x * w1) * inv);
    o.y = f2bf((o0.y * w0 + o1.y * w1) * inv);
    o.z = f2bf((o0.z * w0 + o1.z * w1) * inv);
    o.w = f2bf((o0.w * w0 + o1.w * w1) * inv);
    *reinterpret_cast<ushort4*>(AO + off) = o;
}

// ---------------------------------------------------------------------------
// Output GEMM — pure m97 structure (same as qkvgemm Q path): bf16 AO via
// gload16 with per-lane XOR'd source granule, pre-swizzled woutT, f32 out.
// ---------------------------------------------------------------------------
__global__ __launch_bounds__(256) void ogemm(const u16* __restrict__ AO,
                                             const u16* __restrict__ Bt,
                                             float* __restrict__ C) {
    __shared__ u16 As[64 * 64];
    __shared__ u16 Bs[128 * 64];
    const int nwg = gridDim.x * gridDim.y;
    const int id  = blockIdx.y * gridDim.x + blockIdx.x;
    const int sw  = (id & 7) * (nwg >> 3) + (id >> 3);
    const int bx  = sw % gridDim.x, by = sw / gridDim.x;
    const int tid = threadIdx.x, lane = tid & 63, w = tid >> 6;
    const int wr = w >> 1, wc = w & 1;
    const int row0 = by * 64, col0 = bx * 128;
    const int MROW = wr * 32;
    const int x7   = lane & 7;
    const int lrow = lane >> 3, lcol = (lane & 7) * 8;
    const int swcol = lcol ^ ((lrow & 7) << 3);

    f32x4 acc[2][4];
#pragma unroll
    for (int m = 0; m < 2; ++m)
#pragma unroll
        for (int n = 0; n < 4; ++n) acc[m][n] = (f32x4){0.f, 0.f, 0.f, 0.f};

    for (int k0 = 0; k0 < 1024; k0 += 64) {
        __syncthreads();
#pragma unroll
        for (int p = 0; p < 2; ++p) {
            const int base = w * 512 + p * 2048;
            const int row  = (base >> 6) + lrow;
            gload16(AO + (size_t)(row0 + row) * 1024 + k0 + swcol, &As[base]);
        }
#pragma unroll
        for (int p = 0; p < 4; ++p) {
            const int base = w * 512 + p * 2048;
            const int row  = (base >> 6) + lrow;
            gload16(Bt + (size_t)(col0 + row) * 1024 + k0 + lcol, &Bs[base]);
        }
        __syncthreads();
#pragma unroll
        for (int kk = 0; kk < 2; ++kk) {
            bf16x8 af[2], bfr[4];
            const int G = ((kk * 4 + (lane >> 4)) ^ x7) * 8;
#pragma unroll
            for (int m = 0; m < 2; ++m)
                af[m] = *reinterpret_cast<const bf16x8*>(
                    &As[(MROW + m * 16 + (lane & 15)) * 64 + G]);
#pragma unroll
            for (int n = 0; n < 4; ++n)
                bfr[n] = *reinterpret_cast<const bf16x8*>(
                    &Bs[(wc * 64 + n * 16 + (lane & 15)) * 64 + G]);
#pragma unroll
            for (int m = 0; m < 2; ++m)
#pragma unroll
                for (int n = 0; n < 4; ++n)
                    acc[m][n] = __builtin_amdgcn_mfma_f32_16x16x32_bf16(
                        af[m], bfr[n], acc[m][n], 0, 0, 0);
        }
    }
#pragma unroll
    for (int m = 0; m < 2; ++m)
#pragma unroll
        for (int n = 0; n < 4; ++n) {
            const int gc = col0 + wc * 64 + n * 16 + (lane & 15);
#pragma unroll
            for (int r = 0; r < 4; ++r) {
                const int gr = row0 + MROW + m * 16 + (lane >> 4) * 4 + r;
                C[(size_t)gr * 1024 + gc] = acc[m][n][r];
            }
        }
}

// ---------------------------------------------------------------------------
// Launch.  Workspace (ws >= 80 MB):
//   0-16 KT | 16-32 VT | 32-48 kvbf -> Opart[2] | 48-52 Qb | 52-56 wkvT
//  56-58 wqT | 58-60 woutT | 60-60.5 m_ws,l_ws | 64-68 qbf -> AO
// ---------------------------------------------------------------------------
extern "C" void kernel_launch(void* const* d_in, const int* in_sizes, int n_in,
                              void* d_out, int out_size, void* d_ws, size_t ws_size,
                              hipStream_t stream) {
    const float* query     = (const float*)d_in[0];
    const float* key_value = (const float*)d_in[1];
    const float* w_q       = (const float*)d_in[2];
    const float* w_kv      = (const float*)d_in[3];
    const float* w_out     = (const float*)d_in[4];
    float* out = (float*)d_out;

    char* ws = (char*)d_ws;
    const size_t MB = 1024 * 1024;
    u16*   KT    = (u16*)(ws);
    u16*   VT    = (u16*)(ws + 16 * MB);
    u16*   kvbf  = (u16*)(ws + 32 * MB);   // dead after qkvgemm
    float* Opart = (float*)(ws + 32 * MB); // written by attn
    u16*   Qb    = (u16*)(ws + 48 * MB);
    u16*   wkvT  = (u16*)(ws + 52 * MB);
    u16*   wqT   = (u16*)(ws + 56 * MB);
    u16*   woutT = (u16*)(ws + 58 * MB);
    float* m_wsp = (float*)(ws + 60 * MB);
    float* l_wsp = (float*)(ws + 60 * MB + 256 * 1024);
    u16*   qbf   = (u16*)(ws + 64 * MB);   // dead after qkvgemm
    u16*   AO    = (u16*)(ws + 64 * MB);   // written by combine

    dim3 blk(256);

    // 1) weight transposes (swizzled) + activation casts, one launch
    prep_all<<<6144, blk, 0, stream>>>(w_q, w_kv, w_out, query, key_value,
                                       wqT, wkvT, woutT, qbf, kvbf);

    // 2) FUSED Q + KV projections (m97 structure)
    qkvgemm<<<1280, blk, 0, stream>>>(qbf, kvbf, wqT, wkvT, Qb, KT, VT);

    // 3) split-K flash attention (R13 proven: 32x32 MFMA, in-register P)
    attn_mfma<<<dim3(KSPLIT * 256), blk, 0, stream>>>(
        Qb, KT, VT, Opart, m_wsp, l_wsp);

    // 4) combine partials -> bf16 AO (read Opart once, not 8x)
    attn_combine<<<2048, blk, 0, stream>>>(Opart, m_wsp, l_wsp, AO);

    // 5) output GEMM (pure m97, gload16 A staging)
    ogemm<<<dim3(8, 32), blk, 0, stream>>>(AO, woutT, out);
}